// Round 5
// baseline (92.678 us; speedup 1.0000x reference)
//
#include <hip/hip_runtime.h>
#include <hip/hip_bf16.h>

#define M_DIM 8192
#define N_DIM 8192

typedef short short8 __attribute__((ext_vector_type(8)));
typedef float f32x4 __attribute__((ext_vector_type(4)));

static __device__ __forceinline__ short f2bf(float f) {
    __hip_bfloat16 h = __float2bfloat16(f);   // RNE convert
    union { __hip_bfloat16 h; short s; } u;
    u.h = h;
    return u.s;
}

// Kernel 1: activation [64, 8192] f32 -> actT [8192, 64] bf16 (transposed, packed)
__global__ __launch_bounds__(256) void transpose_act(const float* __restrict__ act,
                                                     short* __restrict__ actT) {
    __shared__ float tile[64][65];   // +1 pad: conflict-free column reads
    const int n0 = blockIdx.x * 64;
    const int tid = threadIdx.x;
    #pragma unroll
    for (int i = tid; i < 64 * 64; i += 256) {
        int k = i >> 6, n = i & 63;
        tile[k][n] = act[k * N_DIM + n0 + n];     // coalesced row reads
    }
    __syncthreads();
    #pragma unroll
    for (int i = tid; i < 64 * 64; i += 256) {
        int n = i >> 6, k = i & 63;
        actT[(n0 + n) * 64 + k] = f2bf(tile[k][n]);  // coalesced bf16 writes
    }
}

// Kernel 2: C[m,n] = dq[m,:] @ act[:,n].
// OCCUPANCY-FIRST: tile 64x128, grid 8192, __launch_bounds__(256,5) -> ~20
// waves/CU so the store stream is fed continuously by staggered blocks.
// LDS epilogue shrunk to one 16x128 slab (8 KB) so LDS never caps occupancy.
__global__ __launch_bounds__(256, 5) void gemm_dq(const float* __restrict__ scale,
                                                  const int* __restrict__ offset,
                                                  const int* __restrict__ weight,
                                                  const short* __restrict__ actT,
                                                  float* __restrict__ C) {
    __shared__ float epi[16 * 128];   // 8 KB slab, reused over 4 passes

    const int tid  = threadIdx.x;
    const int lane = tid & 63;
    const int wid  = tid >> 6;
    const int l15  = lane & 15;
    const int l4   = lane >> 4;

    const int bm = (int)blockIdx.x >> 6;     // N_DIM/128 = 64 n-tiles
    const int bn = (int)blockIdx.x & 63;
    const int m0 = bm * 64;
    const int n0 = bn * 128;

    // ---- A fragments: dequantize 4-bit weights directly into registers.
    // All 4 waves share the block's 64 rows (redundant dequant, cheap VALU).
    // Lane: row m = m0+fm*16+(lane&15), k = kh*32+(lane>>4)*8+j => group g=kh*4+l4.
    short8 afrag[2][4];
    #pragma unroll
    for (int kh = 0; kh < 2; ++kh) {
        const int g = kh * 4 + l4;
        #pragma unroll
        for (int fm = 0; fm < 4; ++fm) {
            const int m = m0 + fm * 16 + l15;
            const unsigned w = (unsigned)weight[m * 8 + g];
            const float   s = scale[m * 8 + g];
            const int   off = (int)(((unsigned)offset[m] >> (4 * g)) & 15u);
            short8 a;
            #pragma unroll
            for (int j = 0; j < 8; ++j) {
                const int wv = (int)((w >> (4 * j)) & 15u);
                a[j] = f2bf(s * (float)(wv - off));
            }
            afrag[kh][fm] = a;
        }
    }

    // ---- B fragments: wave's private 32-col slice (16 VGPR only).
    short8 bfrag[2][2];
    #pragma unroll
    for (int kh = 0; kh < 2; ++kh) {
        #pragma unroll
        for (int fl = 0; fl < 2; ++fl) {
            const int n = n0 + wid * 32 + fl * 16 + l15;
            bfrag[kh][fl] = *reinterpret_cast<const short8*>(actT + n * 64 + kh * 32 + l4 * 8);
        }
    }

    // ---- MFMA: 4x2 fragments x 2 k-halves = 16 mfma
    f32x4 acc[4][2] = {};
    #pragma unroll
    for (int fm = 0; fm < 4; ++fm) {
        #pragma unroll
        for (int fl = 0; fl < 2; ++fl) {
            acc[fm][fl] = __builtin_amdgcn_mfma_f32_16x16x32_bf16(
                afrag[0][fm], bfrag[0][fl], acc[fm][fl], 0, 0, 0);
            acc[fm][fl] = __builtin_amdgcn_mfma_f32_16x16x32_bf16(
                afrag[1][fm], bfrag[1][fl], acc[fm][fl], 0, 0, 0);
        }
    }

    // ---- Epilogue: 4 passes of one 16-row slab. Scatter (swizzled, <=2-way
    // bank aliasing) -> barrier -> cooperative 1KB-per-instr row streaming.
    #pragma unroll
    for (int p = 0; p < 4; ++p) {
        if (p) __syncthreads();              // previous pass's reads complete
        #pragma unroll
        for (int fl = 0; fl < 2; ++fl) {
            const int col = wid * 32 + fl * 16 + l15;
            const int sc  = col ^ (l4 << 2) ^ ((l4 & 1) << 4);
            #pragma unroll
            for (int j = 0; j < 4; ++j) {
                const int row16 = l4 * 4 + j;
                epi[row16 * 128 + sc] = acc[p][fl][j];
            }
        }
        __syncthreads();
        #pragma unroll
        for (int s = 0; s < 2; ++s) {
            const int row16 = wid * 4 + s * 2 + (lane >> 5);   // 2 rows per instr
            const int key   = (row16 >> 2) & 3;
            const int c4    = (lane & 31) * 4;
            const f32x4 v = *reinterpret_cast<const f32x4*>(
                &epi[row16 * 128 + (c4 ^ (key << 2) ^ ((key & 1) << 4))]);
            __builtin_nontemporal_store(v, reinterpret_cast<f32x4*>(
                &C[(size_t)(m0 + p * 16 + row16) * N_DIM + n0 + c4]));
        }
    }
}

extern "C" void kernel_launch(void* const* d_in, const int* in_sizes, int n_in,
                              void* d_out, int out_size, void* d_ws, size_t ws_size,
                              hipStream_t stream) {
    const float* scale  = (const float*)d_in[0];
    const int*   offset = (const int*)d_in[1];
    const int*   weight = (const int*)d_in[2];
    const float* act    = (const float*)d_in[3];
    float* out  = (float*)d_out;
    short* actT = (short*)d_ws;   // 8192*64*2 = 1 MB scratch

    transpose_act<<<N_DIM / 64, 256, 0, stream>>>(act, actT);

    const int grid = (M_DIM / 64) * (N_DIM / 128);   // 8192 blocks
    gemm_dq<<<grid, 256, 0, stream>>>(scale, offset, weight, actT, out);
}

// Round 6
// 65.908 us; speedup vs baseline: 1.4062x; 1.4062x over previous
//
#include <hip/hip_runtime.h>
#include <hip/hip_bf16.h>

#define M_DIM 8192
#define N_DIM 8192

typedef short short8 __attribute__((ext_vector_type(8)));
typedef float f32x4 __attribute__((ext_vector_type(4)));

static __device__ __forceinline__ short f2bf(float f) {
    __hip_bfloat16 h = __float2bfloat16(f);   // RNE convert
    union { __hip_bfloat16 h; short s; } u;
    u.h = h;
    return u.s;
}

// Kernel 1: activation [64, 8192] f32 -> actT [8192, 64] bf16 (transposed, packed)
__global__ __launch_bounds__(256) void transpose_act(const float* __restrict__ act,
                                                     short* __restrict__ actT) {
    __shared__ float tile[64][65];   // +1 pad: conflict-free column reads
    const int n0 = blockIdx.x * 64;
    const int tid = threadIdx.x;
    #pragma unroll
    for (int i = tid; i < 64 * 64; i += 256) {
        int k = i >> 6, n = i & 63;
        tile[k][n] = act[k * N_DIM + n0 + n];     // coalesced row reads
    }
    __syncthreads();
    #pragma unroll
    for (int i = tid; i < 64 * 64; i += 256) {
        int n = i >> 6, k = i & 63;
        actT[(n0 + n) * 64 + k] = f2bf(tile[k][n]);  // coalesced bf16 writes
    }
}

// Kernel 2: C[m,n] = dq[m,:] @ act[:,n].
// PIPELINED-PERSISTENT: grid 512 (2 blocks/CU, zero tail). Each block keeps bn
// fixed (B fragments loaded once, reused x8) and walks 8 M-tiles of 128x128
// with NO block barriers. Stores are fire-and-forget; tile t+1's dequant VALU
// issues while tile t's stores drain -> write pipe continuously fed.
__global__ __launch_bounds__(256, 2) void gemm_dq(const float* __restrict__ scale,
                                                  const int* __restrict__ offset,
                                                  const int* __restrict__ weight,
                                                  const short* __restrict__ actT,
                                                  float* __restrict__ C) {
    // wave-private staging: 64 rows x 32 cols f32 = 8 KB per wave, 32 KB per block
    __shared__ float cs[4][64 * 32];

    const int tid  = threadIdx.x;
    const int lane = tid & 63;
    const int wid  = tid >> 6;
    const int l15  = lane & 15;
    const int l4   = lane >> 4;

    const int bn = (int)blockIdx.x & 63;      // 64 n-tiles of 128
    const int mg = (int)blockIdx.x >> 6;      // 8 m-groups of 8 tiles
    const int n0   = bn * 128 + (wid & 1) * 64;   // wave's 64-col base
    const int wrow = (wid >> 1) * 64;             // wave's row base within tile

    // ---- B fragments: loaded ONCE, reused across all 8 m-tiles (32 VGPR).
    short8 bfrag[2][4];
    #pragma unroll
    for (int kh = 0; kh < 2; ++kh) {
        #pragma unroll
        for (int fn = 0; fn < 4; ++fn) {
            const int n = n0 + fn * 16 + l15;
            bfrag[kh][fn] = *reinterpret_cast<const short8*>(actT + n * 64 + kh * 32 + l4 * 8);
        }
    }

    float* ws = &cs[wid][0];

    #pragma unroll 2
    for (int t = 0; t < 8; ++t) {
        const int m0 = (mg * 8 + t) * 128 + wrow;

        // ---- A fragments: dequantize 4-bit weights directly into registers.
        // Lane: row m = m0+fm*16+(lane&15), k = kh*32+(lane>>4)*8+j
        // => group g = kh*4+(lane>>4): one weight word, one scale, one offset nibble.
        short8 afrag[2][4];
        #pragma unroll
        for (int kh = 0; kh < 2; ++kh) {
            const int g = kh * 4 + l4;
            #pragma unroll
            for (int fm = 0; fm < 4; ++fm) {
                const int m = m0 + fm * 16 + l15;
                const unsigned w = (unsigned)weight[m * 8 + g];
                const float   s = scale[m * 8 + g];
                const int   off = (int)(((unsigned)offset[m] >> (4 * g)) & 15u);
                short8 a;
                #pragma unroll
                for (int j = 0; j < 8; ++j) {
                    const int wv = (int)((w >> (4 * j)) & 15u);
                    a[j] = f2bf(s * (float)(wv - off));
                }
                afrag[kh][fm] = a;
            }
        }

        // ---- Two passes over the wave's 64-col extent: 32 cols each.
        #pragma unroll
        for (int pass = 0; pass < 2; ++pass) {
            // MFMA: 4x2 fragments x 2 k-halves
            f32x4 acc[4][2] = {};
            #pragma unroll
            for (int fm = 0; fm < 4; ++fm) {
                #pragma unroll
                for (int fl = 0; fl < 2; ++fl) {
                    acc[fm][fl] = __builtin_amdgcn_mfma_f32_16x16x32_bf16(
                        afrag[0][fm], bfrag[0][pass * 2 + fl], acc[fm][fl], 0, 0, 0);
                    acc[fm][fl] = __builtin_amdgcn_mfma_f32_16x16x32_bf16(
                        afrag[1][fm], bfrag[1][pass * 2 + fl], acc[fm][fl], 0, 0, 0);
                }
            }

            // Stage into wave-private LDS with XOR swizzle (2-way = free)
            #pragma unroll
            for (int fm = 0; fm < 4; ++fm) {
                #pragma unroll
                for (int fl = 0; fl < 2; ++fl) {
                    const int col = fl * 16 + l15;
                    #pragma unroll
                    for (int j = 0; j < 4; ++j) {
                        const int row = fm * 16 + l4 * 4 + j;
                        const int swz = ((((col >> 2) ^ (row & 7)) << 2) | (col & 3));
                        ws[row * 32 + swz] = acc[fm][fl][j];
                    }
                }
            }
            // wave-internal RAW on LDS (per-wave, no block barrier)
            asm volatile("s_waitcnt lgkmcnt(0)" ::: "memory");

            // Coalesced read-back + store: 8 lanes cover one row (128B line);
            // stores are fire-and-forget -> overlap next tile's dequant.
            #pragma unroll
            for (int r = 0; r < 8; ++r) {
                const int row = r * 8 + (lane >> 3);
                const int cb  = lane & 7;
                const f32x4 v = *reinterpret_cast<const f32x4*>(
                    &ws[row * 32 + ((cb ^ (row & 7)) << 2)]);
                const size_t gr = (size_t)(m0 + row);
                const size_t gc = (size_t)(n0 + pass * 32 + cb * 4);
                __builtin_nontemporal_store(v, reinterpret_cast<f32x4*>(&C[gr * N_DIM + gc]));
            }
        }
    }
}

extern "C" void kernel_launch(void* const* d_in, const int* in_sizes, int n_in,
                              void* d_out, int out_size, void* d_ws, size_t ws_size,
                              hipStream_t stream) {
    const float* scale  = (const float*)d_in[0];
    const int*   offset = (const int*)d_in[1];
    const int*   weight = (const int*)d_in[2];
    const float* act    = (const float*)d_in[3];
    float* out  = (float*)d_out;
    short* actT = (short*)d_ws;   // 8192*64*2 = 1 MB scratch

    transpose_act<<<N_DIM / 64, 256, 0, stream>>>(act, actT);

    gemm_dq<<<512, 256, 0, stream>>>(scale, offset, weight, actT, out);
}

// Round 7
// 58.981 us; speedup vs baseline: 1.5713x; 1.1175x over previous
//
#include <hip/hip_runtime.h>
#include <hip/hip_bf16.h>

#define M_DIM 8192
#define N_DIM 8192

typedef short short8 __attribute__((ext_vector_type(8)));
typedef float f32x4 __attribute__((ext_vector_type(4)));

static __device__ __forceinline__ short f2bf(float f) {
    __hip_bfloat16 h = __float2bfloat16(f);   // RNE convert
    union { __hip_bfloat16 h; short s; } u;
    u.h = h;
    return u.s;
}

// Fused single kernel: C[m,n] = dq[m,:] @ act[:,n].
// PIPELINED-PERSISTENT: grid 512 (2 blocks/CU, zero tail). Each block keeps bn
// fixed, builds B fragments ONCE directly from f32 act (no transpose kernel, no
// actT round-trip), then walks 8 M-tiles of 128x128 with NO block barriers.
// Stores are fire-and-forget; tile t+1's dequant issues while tile t's stores
// drain. Co-resident blocks (idx, idx+256 => mg differs by 4) walk tiles with
// a 4-tile rotation so their store bursts alternate on the CU.
__global__ __launch_bounds__(256, 2) void gemm_dq(const float* __restrict__ scale,
                                                  const int* __restrict__ offset,
                                                  const int* __restrict__ weight,
                                                  const float* __restrict__ act,
                                                  float* __restrict__ C) {
    // wave-private staging: 64 rows x 32 cols f32 = 8 KB per wave, 32 KB per block
    __shared__ float cs[4][64 * 32];

    const int tid  = threadIdx.x;
    const int lane = tid & 63;
    const int wid  = tid >> 6;
    const int l15  = lane & 15;
    const int l4   = lane >> 4;

    const int bn = (int)blockIdx.x & 63;      // 64 n-tiles of 128
    const int mg = (int)blockIdx.x >> 6;      // 8 m-groups of 8 tiles
    const int n0   = bn * 128 + (wid & 1) * 64;   // wave's 64-col base
    const int wrow = (wid >> 1) * 64;             // wave's row base within tile

    // ---- B fragments: built ONCE directly from act [64, 8192] f32 (L2/L3-hot),
    // converted to bf16 in-register; reused across all 8 m-tiles (32 VGPR).
    // Element j of fragment (kh,fn) = act[kh*32 + l4*8 + j][n0 + fn*16 + l15].
    short8 bfrag[2][4];
    #pragma unroll
    for (int kh = 0; kh < 2; ++kh) {
        #pragma unroll
        for (int fn = 0; fn < 4; ++fn) {
            const float* ap = act + (size_t)(kh * 32 + l4 * 8) * N_DIM + (n0 + fn * 16 + l15);
            short8 b;
            #pragma unroll
            for (int j = 0; j < 8; ++j) {
                b[j] = f2bf(ap[(size_t)j * N_DIM]);
            }
            bfrag[kh][fn] = b;
        }
    }

    float* ws = &cs[wid][0];
    const int rot = ((mg >> 2) & 1) * 4;      // desync co-resident block pair

    #pragma unroll 2
    for (int ti = 0; ti < 8; ++ti) {
        const int t  = (ti + rot) & 7;
        const int m0 = (mg * 8 + t) * 128 + wrow;

        // ---- A fragments: dequantize 4-bit weights directly into registers.
        // Lane: row m = m0+fm*16+(lane&15), k = kh*32+(lane>>4)*8+j
        // => group g = kh*4+(lane>>4): one weight word, one scale, one offset nibble.
        short8 afrag[2][4];
        #pragma unroll
        for (int kh = 0; kh < 2; ++kh) {
            const int g = kh * 4 + l4;
            #pragma unroll
            for (int fm = 0; fm < 4; ++fm) {
                const int m = m0 + fm * 16 + l15;
                const unsigned w = (unsigned)weight[m * 8 + g];
                const float   s = scale[m * 8 + g];
                const int   off = (int)(((unsigned)offset[m] >> (4 * g)) & 15u);
                short8 a;
                #pragma unroll
                for (int j = 0; j < 8; ++j) {
                    const int wv = (int)((w >> (4 * j)) & 15u);
                    a[j] = f2bf(s * (float)(wv - off));
                }
                afrag[kh][fm] = a;
            }
        }

        // ---- Two passes over the wave's 64-col extent: 32 cols each.
        #pragma unroll
        for (int pass = 0; pass < 2; ++pass) {
            // MFMA: 4x2 fragments x 2 k-halves
            f32x4 acc[4][2] = {};
            #pragma unroll
            for (int fm = 0; fm < 4; ++fm) {
                #pragma unroll
                for (int fl = 0; fl < 2; ++fl) {
                    acc[fm][fl] = __builtin_amdgcn_mfma_f32_16x16x32_bf16(
                        afrag[0][fm], bfrag[0][pass * 2 + fl], acc[fm][fl], 0, 0, 0);
                    acc[fm][fl] = __builtin_amdgcn_mfma_f32_16x16x32_bf16(
                        afrag[1][fm], bfrag[1][pass * 2 + fl], acc[fm][fl], 0, 0, 0);
                }
            }

            // Stage into wave-private LDS with XOR swizzle (2-way = free)
            #pragma unroll
            for (int fm = 0; fm < 4; ++fm) {
                #pragma unroll
                for (int fl = 0; fl < 2; ++fl) {
                    const int col = fl * 16 + l15;
                    #pragma unroll
                    for (int j = 0; j < 4; ++j) {
                        const int row = fm * 16 + l4 * 4 + j;
                        const int swz = ((((col >> 2) ^ (row & 7)) << 2) | (col & 3));
                        ws[row * 32 + swz] = acc[fm][fl][j];
                    }
                }
            }
            // wave-internal RAW on LDS (per-wave DS pipe is in-order; belt-and-braces)
            asm volatile("s_waitcnt lgkmcnt(0)" ::: "memory");

            // Coalesced read-back + store: 8 lanes cover one row (128B line);
            // stores are fire-and-forget -> overlap next tile's dequant.
            #pragma unroll
            for (int r = 0; r < 8; ++r) {
                const int row = r * 8 + (lane >> 3);
                const int cb  = lane & 7;
                const f32x4 v = *reinterpret_cast<const f32x4*>(
                    &ws[row * 32 + ((cb ^ (row & 7)) << 2)]);
                const size_t gr = (size_t)(m0 + row);
                const size_t gc = (size_t)(n0 + pass * 32 + cb * 4);
                __builtin_nontemporal_store(v, reinterpret_cast<f32x4*>(&C[gr * N_DIM + gc]));
            }
        }
    }
}

extern "C" void kernel_launch(void* const* d_in, const int* in_sizes, int n_in,
                              void* d_out, int out_size, void* d_ws, size_t ws_size,
                              hipStream_t stream) {
    const float* scale  = (const float*)d_in[0];
    const int*   offset = (const int*)d_in[1];
    const int*   weight = (const int*)d_in[2];
    const float* act    = (const float*)d_in[3];
    float* out  = (float*)d_out;

    gemm_dq<<<512, 256, 0, stream>>>(scale, offset, weight, act, out);
}

// Round 8
// 51.148 us; speedup vs baseline: 1.8120x; 1.1531x over previous
//
#include <hip/hip_runtime.h>
#include <hip/hip_bf16.h>

#define M_DIM 8192
#define N_DIM 8192

typedef short short8 __attribute__((ext_vector_type(8)));
typedef float f32x4 __attribute__((ext_vector_type(4)));

static __device__ __forceinline__ short f2bf(float f) {
    __hip_bfloat16 h = __float2bfloat16(f);   // RNE convert
    union { __hip_bfloat16 h; short s; } u;
    u.h = h;
    return u.s;
}

// Fused single kernel: C[m,n] = dq[m,:] @ act[:,n].
// PIPELINED-PERSISTENT (R7 skeleton): grid 512 (2 blocks/CU, zero tail), bn
// fixed per block, B fragments built once from f32 act, 8 M-tiles walked with
// no block barriers, fire-and-forget stores overlapping next tile's dequant.
// NEW (R8): wave owns 32 rows x 128 cols -> every C-row receives its full
// 512B segment in one pass (4x fewer DRAM activates per byte; was 128B/pass).
__global__ __launch_bounds__(256, 2) void gemm_dq(const float* __restrict__ scale,
                                                  const int* __restrict__ offset,
                                                  const int* __restrict__ weight,
                                                  const float* __restrict__ act,
                                                  float* __restrict__ C) {
    // wave-private staging: 16 rows x 132 cols f32 (pad -> <=2-way conflicts)
    __shared__ float cs[4][16 * 132];

    const int tid  = threadIdx.x;
    const int lane = tid & 63;
    const int wid  = tid >> 6;
    const int l15  = lane & 15;
    const int l4   = lane >> 4;

    const int bn = (int)blockIdx.x & 63;      // 64 n-tiles of 128
    const int mg = (int)blockIdx.x >> 6;      // 8 m-groups of 8 tiles
    const int n0 = bn * 128;                  // block's 128-col extent

    // ---- B fragments: built ONCE from act [64, 8192] f32 (L2/L3-hot),
    // converted to bf16 in-register; reused across all 8 m-tiles.
    // Element j of fragment (kh,fn) = act[kh*32 + l4*8 + j][n0 + fn*16 + l15].
    short8 bfrag[2][8];
    #pragma unroll
    for (int kh = 0; kh < 2; ++kh) {
        #pragma unroll
        for (int fn = 0; fn < 8; ++fn) {
            const float* ap = act + (size_t)(kh * 32 + l4 * 8) * N_DIM + (n0 + fn * 16 + l15);
            short8 b;
            #pragma unroll
            for (int j = 0; j < 8; ++j) {
                b[j] = f2bf(ap[(size_t)j * N_DIM]);
            }
            bfrag[kh][fn] = b;
        }
    }

    float* ws = &cs[wid][0];
    const int rot = ((mg >> 2) & 1) * 4;      // desync co-resident block pair

    #pragma unroll 2
    for (int ti = 0; ti < 8; ++ti) {
        const int t  = (ti + rot) & 7;
        const int m0 = (mg * 8 + t) * 128 + wid * 32;   // wave's 32-row slab

        // ---- Process the wave's two 16-row fragments one at a time
        // (keeps acc live-set at 32 VGPR).
        #pragma unroll
        for (int fm = 0; fm < 2; ++fm) {
            // A fragments: dequantize 4-bit weights directly into registers.
            // Lane: row m = m0+fm*16+(lane&15), k = kh*32+(lane>>4)*8+j
            // => group g = kh*4+(lane>>4): one word, one scale, one offset nibble.
            short8 afrag[2];
            #pragma unroll
            for (int kh = 0; kh < 2; ++kh) {
                const int g = kh * 4 + l4;
                const int m = m0 + fm * 16 + l15;
                const unsigned w = (unsigned)weight[m * 8 + g];
                const float   s = scale[m * 8 + g];
                const int   off = (int)(((unsigned)offset[m] >> (4 * g)) & 15u);
                short8 a;
                #pragma unroll
                for (int j = 0; j < 8; ++j) {
                    const int wv = (int)((w >> (4 * j)) & 15u);
                    a[j] = f2bf(s * (float)(wv - off));
                }
                afrag[kh] = a;
            }

            // MFMA: 16 rows x 128 cols = 8 fn-fragments x 2 k-halves
            f32x4 acc[8] = {};
            #pragma unroll
            for (int fn = 0; fn < 8; ++fn) {
                acc[fn] = __builtin_amdgcn_mfma_f32_16x16x32_bf16(
                    afrag[0], bfrag[0][fn], acc[fn], 0, 0, 0);
                acc[fn] = __builtin_amdgcn_mfma_f32_16x16x32_bf16(
                    afrag[1], bfrag[1][fn], acc[fn], 0, 0, 0);
            }

            // Stage 16x128 into padded LDS (2-way bank aliasing = free).
            // C/D layout: col = fn*16 + l15, row16 = l4*4 + j.
            #pragma unroll
            for (int fn = 0; fn < 8; ++fn) {
                const int col = fn * 16 + l15;
                #pragma unroll
                for (int j = 0; j < 4; ++j) {
                    const int row16 = l4 * 4 + j;
                    ws[row16 * 132 + col] = acc[fn][j];
                }
            }
            // wave-internal RAW on LDS (per-wave DS pipe is in-order)
            asm volatile("s_waitcnt lgkmcnt(0)" ::: "memory");

            // Readback + store: each instr = 2 rows x 512B contiguous; rows
            // ascend so each DRAM activate moves a full 512B segment.
            #pragma unroll
            for (int s = 0; s < 8; ++s) {
                const int row16 = s * 2 + (lane >> 5);
                const int c4    = (lane & 31) * 4;
                const f32x4 v = *reinterpret_cast<const f32x4*>(&ws[row16 * 132 + c4]);
                const size_t gr = (size_t)(m0 + fm * 16 + row16);
                __builtin_nontemporal_store(v, reinterpret_cast<f32x4*>(
                    &C[gr * N_DIM + n0 + c4]));
            }
        }
    }
}

extern "C" void kernel_launch(void* const* d_in, const int* in_sizes, int n_in,
                              void* d_out, int out_size, void* d_ws, size_t ws_size,
                              hipStream_t stream) {
    const float* scale  = (const float*)d_in[0];
    const int*   offset = (const int*)d_in[1];
    const int*   weight = (const int*)d_in[2];
    const float* act    = (const float*)d_in[3];
    float* out  = (float*)d_out;

    gemm_dq<<<512, 256, 0, stream>>>(scale, offset, weight, act, out);
}